// Round 9
// baseline (321.371 us; speedup 1.0000x reference)
//
#include <hip/hip_runtime.h>
#include <hip/hip_bf16.h>
#include <math.h>

typedef __hip_bfloat16  bf16_t;
typedef __attribute__((ext_vector_type(8))) short  short8;   // 8 bf16 (4 VGPRs)
typedef __attribute__((ext_vector_type(4))) float  f32x4;
typedef __attribute__((ext_vector_type(4))) int    intv4;    // for nontemporal int4 loads

#define CDIM 128
#define KCAP 32            // fixed CSR slots per node; overflow -> exact spill list

static __device__ __forceinline__ float sigm(float x){ return 1.0f/(1.0f+__expf(-x)); }
static __device__ __forceinline__ float bflo(unsigned u){ return __builtin_bit_cast(float, u << 16); }
static __device__ __forceinline__ float bfhi(unsigned u){ return __builtin_bit_cast(float, u & 0xffff0000u); }
static __device__ __forceinline__ unsigned short f2bf_u(float f){
    __hip_bfloat16 h = __float2bfloat16(f);
    return __builtin_bit_cast(unsigned short, h);
}
static __device__ __forceinline__ unsigned packbf(float a, float b){
    return (unsigned)f2bf_u(a) | ((unsigned)f2bf_u(b) << 16);
}
static __device__ __forceinline__ short f2bf_s(float f){
    return (short)f2bf_u(f);
}

// ---------- 1. LSTM single step -> w_new in MFMA B-frag layout; also zeroes deg/spillc ----------
// wfrag short index: ((t*8+n0)*64 + quad*16+mm)*8 + jj  <=>  B[k=32t+quad*8+jj][n=n0*16+mm]
__global__ void k_lstm(const float* __restrict__ weight, const float* __restrict__ w_ih,
                       const float* __restrict__ b_ih,   const float* __restrict__ b_hh,
                       short* __restrict__ wfrag, int* __restrict__ zptr, int zcount){
    // fold the memset dispatch: 16384 threads grid-stride zero deg+spillc (~100K ints)
    const int gtid = blockIdx.x*CDIM + threadIdx.x;
    for(int i = gtid; i < zcount; i += CDIM*CDIM) zptr[i] = 0;

    __shared__ float wrow[CDIM];
    const int r = blockIdx.x, j = threadIdx.x;
    wrow[j] = weight[r*CDIM + j];
    __syncthreads();
    const float4* wi = (const float4*)(w_ih + (size_t)j*CDIM);
    const float4* wg = (const float4*)(w_ih + (size_t)(2*CDIM + j)*CDIM);
    const float4* wo = (const float4*)(w_ih + (size_t)(3*CDIM + j)*CDIM);
    const float4* wr = (const float4*)wrow;
    float si = 0.f, sg = 0.f, so = 0.f;
    #pragma unroll 8
    for(int k = 0; k < CDIM/4; k++){
        float4 w4 = wr[k];
        float4 a = wi[k]; si += w4.x*a.x + w4.y*a.y + w4.z*a.z + w4.w*a.w;
        float4 b = wg[k]; sg += w4.x*b.x + w4.y*b.y + w4.z*b.z + w4.w*b.w;
        float4 c = wo[k]; so += w4.x*c.x + w4.y*c.y + w4.z*c.z + w4.w*c.w;
    }
    si += b_ih[j]        + b_hh[j];
    sg += b_ih[2*CDIM+j] + b_hh[2*CDIM+j];
    so += b_ih[3*CDIM+j] + b_hh[3*CDIM+j];
    float c  = sigm(si)*tanhf(sg);           // f-gate * c0 = 0
    float wv = sigm(so)*tanhf(c);
    const int t = r >> 5, quad = (r >> 3) & 3, jj = r & 7;   // uniform per block
    const int n0 = j >> 4, mm = j & 15;
    wfrag[((size_t)((t*8 + n0)*64 + quad*16 + mm))*8 + jj] = f2bf_s(wv);
}

// ---------- 2. FUSED: graph build (atomic wall) + y0 = bf16(x) cast ----------
// Edge atomics run at a fixed memory-side ceiling (~76us standalone for 1.6M edges;
// invariant across R0/R2/R4/R5/R8 restructurings -- rate is insensitive to wave count)
// and leave VALU ~5% / HBM ~20% idle -> the x->bf16 cast rides along (~+9us).
__global__ __launch_bounds__(256) void k_fillcast(const int* __restrict__ src, const int* __restrict__ dst,
        int e, int* __restrict__ cnt, int* __restrict__ csr,
        int2* __restrict__ spill, int* __restrict__ spillc, int nper,
        const float* __restrict__ x, bf16_t* __restrict__ y0, int nf4,
        int castblocks, int edgeblocks){
    if((int)blockIdx.x < castblocks){
        // ---- cast path: grid-stride float4 -> 4x bf16 ----
        const float4* xv = (const float4*)x;
        uint2* yv = (uint2*)y0;
        const int t0   = blockIdx.x*256 + threadIdx.x;
        const int step = castblocks*256;
        for(int i = t0; i < nf4; i += step){
            float4 v = xv[i];
            uint2 o; o.x = packbf(v.x, v.y); o.y = packbf(v.z, v.w);
            yv[i] = o;
        }
        return;
    }
    // ---- edge path (R4 structure: best measured) ----
    const int bid = (int)blockIdx.x - castblocks;
    const int grp = bid & 7;
    const int lo  = grp*nper, hi = lo + nper;
    const int tid = (bid >> 3)*256 + threadIdx.x;
    const int nt  = (edgeblocks >> 3)*256;
    const int e4  = e >> 2;
    const intv4* d4 = (const intv4*)dst;
    const intv4* s4 = (const intv4*)src;
    for(int i = tid; i < e4; i += nt){
        intv4 d = __builtin_nontemporal_load(d4 + i);
        intv4 s = __builtin_nontemporal_load(s4 + i);
        #pragma unroll
        for(int c = 0; c < 4; c++){
            int di = d[c];
            if(di >= lo && di < hi){
                int p = atomicAdd(&cnt[di], 1);
                if(p < KCAP) csr[(size_t)di*KCAP + p] = s[c];
                else { int sp = atomicAdd(spillc, 1); spill[sp] = make_int2(s[c], di); }
            }
        }
    }
    for(int k = e4*4 + tid; k < e; k += nt){   // scalar tail (e % 4 elements)
        int di = dst[k];
        if(di >= lo && di < hi){
            int sv = src[k];
            int p = atomicAdd(&cnt[di], 1);
            if(p < KCAP) csr[(size_t)di*KCAP + p] = sv;
            else { int sp = atomicAdd(spillc, 1); spill[sp] = make_int2(sv, di); }
        }
    }
}

// ---------- 3. aggregate, FEATURE-SPLIT two-pass ----------
// agg[i] = bf16( di * ( sum_j dinv_j*y0_j + di*y0_i ) ), one wave per (node, feature-half).
// Blocks [0,rb) process features 0..63 (row-half 0), blocks [rb,2rb) features 64..127.
// Block-scheduling order temporally separates the passes, so the hot gather working set
// is one 12.8MB y-half at a time (vs 25.6MB) -> higher per-XCD L2 residency, less L3
// traffic. Cost: csr/deg re-read per half (13MB stream). Gather stays 8-deep per quad
// (32 half-row lines in flight per wave). Each neighbor access is exactly ONE 128B line.
__global__ __launch_bounds__(256) void k_agg(const bf16_t* __restrict__ y, const int* __restrict__ csr,
                      const int* __restrict__ deg, const int2* __restrict__ spill,
                      const int* __restrict__ spillc, bf16_t* __restrict__ agg, int n, int rb){
    int b = (int)blockIdx.x;
    const int half = (b >= rb) ? 1 : 0;
    if(half) b -= rb;
    const int node = (int)(((size_t)b*256 + threadIdx.x) >> 6);
    if(node >= n) return;
    const int lane = threadIdx.x & 63;
    const int q = lane >> 4, f = lane & 15;
    const int   cnt = deg[node];
    const float di  = rsqrtf((float)(cnt + 1));
    const int   m   = cnt < KCAP ? cnt : KCAP;
    const size_t hoff = (size_t)half*128 + (size_t)f*8;          // byte offset within row
    uint2 sv = *(const uint2*)((const char*)y + (size_t)node*256 + hoff);   // self half-row
    int jid = (lane < m) ? csr[(size_t)node*KCAP + lane] : 0;

    int jv[8];
    #pragma unroll
    for(int t = 0; t < 8; t++) jv[t] = __shfl(jid, 4*t + q, 64);

    int dgv[8];
    #pragma unroll
    for(int t = 0; t < 8; t++)
        if(4*t + q < m) dgv[t] = deg[jv[t]];                     // broadcast loads, issued first

    uint2 v[8];
    #pragma unroll
    for(int t = 0; t < 8; t++)
        if(4*t + q < m) v[t] = *(const uint2*)((const char*)y + (size_t)jv[t]*256 + hoff);

    float acc[4];
    #pragma unroll
    for(int i = 0; i < 4; i++) acc[i] = 0.f;
    #pragma unroll
    for(int t = 0; t < 8; t++){
        if(4*t + q < m){
            float dj = rsqrtf((float)(dgv[t] + 1));
            acc[0] += dj*bflo(v[t].x); acc[1] += dj*bfhi(v[t].x);
            acc[2] += dj*bflo(v[t].y); acc[3] += dj*bfhi(v[t].y);
        }
    }
    // overflow edges (cold path: spillc == 0 for typical degree distributions)
    int sc = *spillc;
    if(sc > 0){
        for(int t = q; t < sc; t += 4){                // quads split the list; reduce below sums
            int2 sd = spill[t];
            if(sd.y == node){
                float dj = rsqrtf((float)(deg[sd.x] + 1));
                uint2 vv = *(const uint2*)((const char*)y + (size_t)sd.x*256 + hoff);
                acc[0] += dj*bflo(vv.x); acc[1] += dj*bfhi(vv.x);
                acc[2] += dj*bflo(vv.y); acc[3] += dj*bfhi(vv.y);
            }
        }
    }
    #pragma unroll
    for(int i = 0; i < 4; i++){
        acc[i] += __shfl_xor(acc[i], 16, 64);
        acc[i] += __shfl_xor(acc[i], 32, 64);
    }
    if(q == 0){
        uint2 o;
        o.x = packbf(di*(acc[0] + di*bflo(sv.x)), di*(acc[1] + di*bfhi(sv.x)));
        o.y = packbf(di*(acc[2] + di*bflo(sv.y)), di*(acc[3] + di*bfhi(sv.y)));
        *(uint2*)((char*)agg + (size_t)node*256 + hoff) = o;
    }
}

// ---------- 4. out = agg(bf16) @ W(bf16 frags) via MFMA, f32 out ----------
__global__ __launch_bounds__(256) void k_mgemm(const bf16_t* __restrict__ agg,
                                               const short* __restrict__ wfrag,
                                               float* __restrict__ out, int n){
    const int wid  = blockIdx.x*4 + (threadIdx.x >> 6);   // one wave per 16-row stripe
    const int row0 = wid*16;
    if(row0 >= n) return;
    const int lane = threadIdx.x & 63;
    const int m    = lane & 15, quad = lane >> 4;
    int arow = row0 + m; if(arow > n-1) arow = n-1;
    const short* ap = (const short*)agg + (size_t)arow*CDIM + quad*8;
    short8 a0 = *(const short8*)(ap);
    short8 a1 = *(const short8*)(ap + 32);
    short8 a2 = *(const short8*)(ap + 64);
    short8 a3 = *(const short8*)(ap + 96);
    const short8* bp = (const short8*)wfrag;
    float* orow = out + (size_t)(row0 + quad*4)*CDIM + m;
    const bool full = (row0 + 16 <= n);
    #pragma unroll
    for(int n0 = 0; n0 < 8; n0++){
        f32x4 acc = {0.f, 0.f, 0.f, 0.f};
        acc = __builtin_amdgcn_mfma_f32_16x16x32_bf16(a0, bp[(0*8+n0)*64 + lane], acc, 0, 0, 0);
        acc = __builtin_amdgcn_mfma_f32_16x16x32_bf16(a1, bp[(1*8+n0)*64 + lane], acc, 0, 0, 0);
        acc = __builtin_amdgcn_mfma_f32_16x16x32_bf16(a2, bp[(2*8+n0)*64 + lane], acc, 0, 0, 0);
        acc = __builtin_amdgcn_mfma_f32_16x16x32_bf16(a3, bp[(3*8+n0)*64 + lane], acc, 0, 0, 0);
        if(full){
            #pragma unroll
            for(int r = 0; r < 4; r++)
                orow[(size_t)r*CDIM + n0*16] = acc[r];
        } else {
            #pragma unroll
            for(int r = 0; r < 4; r++)
                if(row0 + quad*4 + r < n) orow[(size_t)r*CDIM + n0*16] = acc[r];
        }
    }
}

extern "C" void kernel_launch(void* const* d_in, const int* in_sizes, int n_in,
                              void* d_out, int out_size, void* d_ws, size_t ws_size,
                              hipStream_t stream){
    const float* x      = (const float*)d_in[0];
    const int*   ei     = (const int*)  d_in[1];
    const float* weight = (const float*)d_in[2];
    const float* w_ih   = (const float*)d_in[3];
    // d_in[4] = w_hh: zero forward contribution (h0 = 0)
    const float* b_ih   = (const float*)d_in[5];
    const float* b_hh   = (const float*)d_in[6];
    float* out = (float*)d_out;

    const int n = in_sizes[0]/CDIM;   // 100000
    const int e = in_sizes[1]/2;      // 1600000
    const int* srcp = ei;
    const int* dstp = ei + e;

    auto alignup = [](size_t v){ return (v + 255) & ~(size_t)255; };
    char*  base = (char*)d_ws;
    size_t o = 0;
    short*  wfrag  = (short*) (base+o); o += alignup((size_t)CDIM*CDIM*sizeof(short));
    int*    deg    = (int*)   (base+o); o += alignup((size_t)n*4);          // | contiguous
    int*    spillc = (int*)   (base+o); o += alignup(256);                  // | zero region
    size_t  zbytes = (size_t)((char*)(base+o) - (char*)deg);
    int*    csr    = (int*)   (base+o); o += alignup((size_t)n*KCAP*4);     // 12.8 MB padded CSR
    bf16_t* aggbuf = (bf16_t*)(base+o); // n*CDIM*2 bytes  (~38.9 MB total: proven R2-R8)

    // d_out (51.2 MB) doubles as scratch until k_mgemm overwrites it last:
    //   [0, 25.6 MB)  : y0 = bf16(x)  (unscaled)
    //   [25.6, 38.4)  : spill list (int2) -- normally empty
    bf16_t* y0    = (bf16_t*)d_out;
    int2*   spill = (int2*)((char*)d_out + (size_t)n*CDIM*sizeof(bf16_t));

    const int nper  = (n + 7)/8;              // dst-range per XCD group
    const int castb = 512;                    // cast blocks (retire early)
    const int edgeb = 2048;                   // 256 blocks per XCD group
    const int rb = (n + 3)/4;                 // k_agg: 4 waves (nodes) per block, PER HALF
    const int gw = (n + 15)/16;               // k_mgemm: 16-row stripes
    const int gb = (gw + 3)/4;

    k_lstm    <<<CDIM, CDIM, 0, stream>>>(weight, w_ih, b_ih, b_hh, wfrag,
                                          deg, (int)(zbytes/4));   // also zeroes deg+spillc
    k_fillcast<<<castb+edgeb, 256, 0, stream>>>(srcp, dstp, e, deg, csr, spill, spillc, nper,
                                                x, y0, n*CDIM/4, castb, edgeb);
    k_agg     <<<2*rb, 256, 0, stream>>>(y0, csr, deg, spill, spillc, aggbuf, n, rb);
    k_mgemm   <<<gb, 256, 0, stream>>>(aggbuf, wfrag, out, n);
}

// Round 11
// 277.590 us; speedup vs baseline: 1.1577x; 1.1577x over previous
//
#include <hip/hip_runtime.h>
#include <hip/hip_bf16.h>
#include <math.h>

typedef __hip_bfloat16  bf16_t;
typedef __attribute__((ext_vector_type(8))) short  short8;   // 8 bf16 (4 VGPRs)
typedef __attribute__((ext_vector_type(4))) float  f32x4;
typedef __attribute__((ext_vector_type(4))) int    intv4;    // for nontemporal int4 loads

#define CDIM 128
#define KCAP 32            // fixed CSR slots per node; overflow -> exact spill list

static __device__ __forceinline__ float sigm(float x){ return 1.0f/(1.0f+__expf(-x)); }
static __device__ __forceinline__ float bflo(unsigned u){ return __builtin_bit_cast(float, u << 16); }
static __device__ __forceinline__ float bfhi(unsigned u){ return __builtin_bit_cast(float, u & 0xffff0000u); }
static __device__ __forceinline__ unsigned short f2bf_u(float f){
    __hip_bfloat16 h = __float2bfloat16(f);
    return __builtin_bit_cast(unsigned short, h);
}
static __device__ __forceinline__ unsigned packbf(float a, float b){
    return (unsigned)f2bf_u(a) | ((unsigned)f2bf_u(b) << 16);
}
static __device__ __forceinline__ short f2bf_s(float f){
    return (short)f2bf_u(f);
}

// ---------- 1. LSTM single step -> w_new in MFMA B-frag layout; also zeroes deg/spillc ----------
// wfrag short index: ((t*8+n0)*64 + quad*16+mm)*8 + jj  <=>  B[k=32t+quad*8+jj][n=n0*16+mm]
__global__ void k_lstm(const float* __restrict__ weight, const float* __restrict__ w_ih,
                       const float* __restrict__ b_ih,   const float* __restrict__ b_hh,
                       short* __restrict__ wfrag, int* __restrict__ zptr, int zcount){
    // fold the memset dispatch: 16384 threads grid-stride zero deg+spillc (~100K ints)
    const int gtid = blockIdx.x*CDIM + threadIdx.x;
    for(int i = gtid; i < zcount; i += CDIM*CDIM) zptr[i] = 0;

    __shared__ float wrow[CDIM];
    const int r = blockIdx.x, j = threadIdx.x;
    wrow[j] = weight[r*CDIM + j];
    __syncthreads();
    const float4* wi = (const float4*)(w_ih + (size_t)j*CDIM);
    const float4* wg = (const float4*)(w_ih + (size_t)(2*CDIM + j)*CDIM);
    const float4* wo = (const float4*)(w_ih + (size_t)(3*CDIM + j)*CDIM);
    const float4* wr = (const float4*)wrow;
    float si = 0.f, sg = 0.f, so = 0.f;
    #pragma unroll 8
    for(int k = 0; k < CDIM/4; k++){
        float4 w4 = wr[k];
        float4 a = wi[k]; si += w4.x*a.x + w4.y*a.y + w4.z*a.z + w4.w*a.w;
        float4 b = wg[k]; sg += w4.x*b.x + w4.y*b.y + w4.z*b.z + w4.w*b.w;
        float4 c = wo[k]; so += w4.x*c.x + w4.y*c.y + w4.z*c.z + w4.w*c.w;
    }
    si += b_ih[j]        + b_hh[j];
    sg += b_ih[2*CDIM+j] + b_hh[2*CDIM+j];
    so += b_ih[3*CDIM+j] + b_hh[3*CDIM+j];
    float c  = sigm(si)*tanhf(sg);           // f-gate * c0 = 0
    float wv = sigm(so)*tanhf(c);
    const int t = r >> 5, quad = (r >> 3) & 3, jj = r & 7;   // uniform per block
    const int n0 = j >> 4, mm = j & 15;
    wfrag[((size_t)((t*8 + n0)*64 + quad*16 + mm))*8 + jj] = f2bf_s(wv);
}

// ---------- 2. FUSED: graph build (atomic wall) + y0 = bf16(x) cast ----------
// Edge atomics run at a fixed memory-side ceiling (~76us standalone for 1.6M edges;
// invariant across R0/R2/R4/R5/R8 restructurings -- rate insensitive to wave count)
// and leave VALU ~5% / HBM ~20% idle -> the x->bf16 cast rides along (~+9us).
__global__ __launch_bounds__(256) void k_fillcast(const int* __restrict__ src, const int* __restrict__ dst,
        int e, int* __restrict__ cnt, int* __restrict__ csr,
        int2* __restrict__ spill, int* __restrict__ spillc, int nper,
        const float* __restrict__ x, bf16_t* __restrict__ y0, int nf4,
        int castblocks, int edgeblocks){
    if((int)blockIdx.x < castblocks){
        // ---- cast path: grid-stride float4 -> 4x bf16 ----
        const float4* xv = (const float4*)x;
        uint2* yv = (uint2*)y0;
        const int t0   = blockIdx.x*256 + threadIdx.x;
        const int step = castblocks*256;
        for(int i = t0; i < nf4; i += step){
            float4 v = xv[i];
            uint2 o; o.x = packbf(v.x, v.y); o.y = packbf(v.z, v.w);
            yv[i] = o;
        }
        return;
    }
    // ---- edge path (R4 structure: best measured) ----
    const int bid = (int)blockIdx.x - castblocks;
    const int grp = bid & 7;
    const int lo  = grp*nper, hi = lo + nper;
    const int tid = (bid >> 3)*256 + threadIdx.x;
    const int nt  = (edgeblocks >> 3)*256;
    const int e4  = e >> 2;
    const intv4* d4 = (const intv4*)dst;
    const intv4* s4 = (const intv4*)src;
    for(int i = tid; i < e4; i += nt){
        intv4 d = __builtin_nontemporal_load(d4 + i);
        intv4 s = __builtin_nontemporal_load(s4 + i);
        #pragma unroll
        for(int c = 0; c < 4; c++){
            int di = d[c];
            if(di >= lo && di < hi){
                int p = atomicAdd(&cnt[di], 1);
                if(p < KCAP) csr[(size_t)di*KCAP + p] = s[c];
                else { int sp = atomicAdd(spillc, 1); spill[sp] = make_int2(s[c], di); }
            }
        }
    }
    for(int k = e4*4 + tid; k < e; k += nt){   // scalar tail (e % 4 elements)
        int di = dst[k];
        if(di >= lo && di < hi){
            int sv = src[k];
            int p = atomicAdd(&cnt[di], 1);
            if(p < KCAP) csr[(size_t)di*KCAP + p] = sv;
            else { int sp = atomicAdd(spillc, 1); spill[sp] = make_int2(sv, di); }
        }
    }
}

// ---------- 3. aggregate: agg[i] = bf16( di * ( sum_j dinv_j*y0_j + di*y0_i ) ) ----------
// One wave per node (NO block coupling -- fused variants R3/R7 regressed; feature-split
// R9 regressed). quad q handles neighbors (4t+q); m <= KCAP = 32 -> FULLY UNROLLED:
// 8 deg loads + 8 full-row uint4 gathers per quad issued back-to-back -> 40 loads in
// flight per wave. At FETCH ~190MB @ ~2.5TB/s L2-miss service this is the floor.
__global__ __launch_bounds__(256) void k_agg(const bf16_t* __restrict__ y, const int* __restrict__ csr,
                      const int* __restrict__ deg, const int2* __restrict__ spill,
                      const int* __restrict__ spillc, bf16_t* __restrict__ agg, int n){
    const int node = (int)(((size_t)blockIdx.x*256 + threadIdx.x) >> 6);
    if(node >= n) return;
    const int lane = threadIdx.x & 63;
    const int q = lane >> 4, f = lane & 15;
    const int   cnt = deg[node];
    const float di  = rsqrtf((float)(cnt + 1));
    const int   m   = cnt < KCAP ? cnt : KCAP;
    const uint4* yrow = (const uint4*)y;               // 16 uint4 per row
    uint4 sv = yrow[(size_t)node*16 + f];              // self row (unscaled bf16)
    int jid = (lane < m) ? csr[(size_t)node*KCAP + lane] : 0;

    int jv[8];
    #pragma unroll
    for(int t = 0; t < 8; t++) jv[t] = __shfl(jid, 4*t + q, 64);

    int dgv[8];
    #pragma unroll
    for(int t = 0; t < 8; t++)
        if(4*t + q < m) dgv[t] = deg[jv[t]];                 // broadcast loads, issued first

    uint4 v[8];
    #pragma unroll
    for(int t = 0; t < 8; t++)
        if(4*t + q < m) v[t] = yrow[(size_t)jv[t]*16 + f];   // all rows in flight

    float acc[8];
    #pragma unroll
    for(int i = 0; i < 8; i++) acc[i] = 0.f;
    #pragma unroll
    for(int t = 0; t < 8; t++){
        if(4*t + q < m){
            float dj = rsqrtf((float)(dgv[t] + 1));
            acc[0] += dj*bflo(v[t].x); acc[1] += dj*bfhi(v[t].x);
            acc[2] += dj*bflo(v[t].y); acc[3] += dj*bfhi(v[t].y);
            acc[4] += dj*bflo(v[t].z); acc[5] += dj*bfhi(v[t].z);
            acc[6] += dj*bflo(v[t].w); acc[7] += dj*bfhi(v[t].w);
        }
    }
    // overflow edges (cold path: spillc == 0 for typical degree distributions)
    int sc = *spillc;
    if(sc > 0){
        for(int t = q; t < sc; t += 4){                // quads split the list; reduce below sums
            int2 sd = spill[t];
            if(sd.y == node){
                float dj = rsqrtf((float)(deg[sd.x] + 1));
                uint4 vv = yrow[(size_t)sd.x*16 + f];
                acc[0] += dj*bflo(vv.x); acc[1] += dj*bfhi(vv.x);
                acc[2] += dj*bflo(vv.y); acc[3] += dj*bfhi(vv.y);
                acc[4] += dj*bflo(vv.z); acc[5] += dj*bfhi(vv.z);
                acc[6] += dj*bflo(vv.w); acc[7] += dj*bfhi(vv.w);
            }
        }
    }
    #pragma unroll
    for(int i = 0; i < 8; i++){
        acc[i] += __shfl_xor(acc[i], 16, 64);
        acc[i] += __shfl_xor(acc[i], 32, 64);
    }
    if(q == 0){
        uint4 o;
        o.x = packbf(di*(acc[0] + di*bflo(sv.x)), di*(acc[1] + di*bfhi(sv.x)));
        o.y = packbf(di*(acc[2] + di*bflo(sv.y)), di*(acc[3] + di*bfhi(sv.y)));
        o.z = packbf(di*(acc[4] + di*bflo(sv.z)), di*(acc[5] + di*bfhi(sv.z)));
        o.w = packbf(di*(acc[6] + di*bflo(sv.w)), di*(acc[7] + di*bfhi(sv.w)));
        ((uint4*)agg)[(size_t)node*16 + f] = o;
    }
}

// ---------- 4. out = agg(bf16) @ W(bf16 frags) via MFMA, f32 out ----------
__global__ __launch_bounds__(256) void k_mgemm(const bf16_t* __restrict__ agg,
                                               const short* __restrict__ wfrag,
                                               float* __restrict__ out, int n){
    const int wid  = blockIdx.x*4 + (threadIdx.x >> 6);   // one wave per 16-row stripe
    const int row0 = wid*16;
    if(row0 >= n) return;
    const int lane = threadIdx.x & 63;
    const int m    = lane & 15, quad = lane >> 4;
    int arow = row0 + m; if(arow > n-1) arow = n-1;
    const short* ap = (const short*)agg + (size_t)arow*CDIM + quad*8;
    short8 a0 = *(const short8*)(ap);
    short8 a1 = *(const short8*)(ap + 32);
    short8 a2 = *(const short8*)(ap + 64);
    short8 a3 = *(const short8*)(ap + 96);
    const short8* bp = (const short8*)wfrag;
    float* orow = out + (size_t)(row0 + quad*4)*CDIM + m;
    const bool full = (row0 + 16 <= n);
    #pragma unroll
    for(int n0 = 0; n0 < 8; n0++){
        f32x4 acc = {0.f, 0.f, 0.f, 0.f};
        acc = __builtin_amdgcn_mfma_f32_16x16x32_bf16(a0, bp[(0*8+n0)*64 + lane], acc, 0, 0, 0);
        acc = __builtin_amdgcn_mfma_f32_16x16x32_bf16(a1, bp[(1*8+n0)*64 + lane], acc, 0, 0, 0);
        acc = __builtin_amdgcn_mfma_f32_16x16x32_bf16(a2, bp[(2*8+n0)*64 + lane], acc, 0, 0, 0);
        acc = __builtin_amdgcn_mfma_f32_16x16x32_bf16(a3, bp[(3*8+n0)*64 + lane], acc, 0, 0, 0);
        if(full){
            #pragma unroll
            for(int r = 0; r < 4; r++)
                orow[(size_t)r*CDIM + n0*16] = acc[r];
        } else {
            #pragma unroll
            for(int r = 0; r < 4; r++)
                if(row0 + quad*4 + r < n) orow[(size_t)r*CDIM + n0*16] = acc[r];
        }
    }
}

extern "C" void kernel_launch(void* const* d_in, const int* in_sizes, int n_in,
                              void* d_out, int out_size, void* d_ws, size_t ws_size,
                              hipStream_t stream){
    const float* x      = (const float*)d_in[0];
    const int*   ei     = (const int*)  d_in[1];
    const float* weight = (const float*)d_in[2];
    const float* w_ih   = (const float*)d_in[3];
    // d_in[4] = w_hh: zero forward contribution (h0 = 0)
    const float* b_ih   = (const float*)d_in[5];
    const float* b_hh   = (const float*)d_in[6];
    float* out = (float*)d_out;

    const int n = in_sizes[0]/CDIM;   // 100000
    const int e = in_sizes[1]/2;      // 1600000
    const int* srcp = ei;
    const int* dstp = ei + e;

    auto alignup = [](size_t v){ return (v + 255) & ~(size_t)255; };
    char*  base = (char*)d_ws;
    size_t o = 0;
    short*  wfrag  = (short*) (base+o); o += alignup((size_t)CDIM*CDIM*sizeof(short));
    int*    deg    = (int*)   (base+o); o += alignup((size_t)n*4);          // | contiguous
    int*    spillc = (int*)   (base+o); o += alignup(256);                  // | zero region
    size_t  zbytes = (size_t)((char*)(base+o) - (char*)deg);
    int*    csr    = (int*)   (base+o); o += alignup((size_t)n*KCAP*4);     // 12.8 MB padded CSR
    bf16_t* aggbuf = (bf16_t*)(base+o); // n*CDIM*2 bytes  (~38.9 MB total: proven R2-R8)

    // d_out (51.2 MB) doubles as scratch until k_mgemm overwrites it last:
    //   [0, 25.6 MB)  : y0 = bf16(x)  (unscaled)
    //   [25.6, 38.4)  : spill list (int2) -- normally empty
    bf16_t* y0    = (bf16_t*)d_out;
    int2*   spill = (int2*)((char*)d_out + (size_t)n*CDIM*sizeof(bf16_t));

    const int nper  = (n + 7)/8;              // dst-range per XCD group
    const int castb = 512;                    // cast blocks (retire early)
    const int edgeb = 1536;                   // 192 blocks per XCD group (R6's measured best)
    const int rb = (n + 3)/4;                 // k_agg: 4 waves (nodes) per block
    const int gw = (n + 15)/16;               // k_mgemm: 16-row stripes
    const int gb = (gw + 3)/4;

    k_lstm    <<<CDIM, CDIM, 0, stream>>>(weight, w_ih, b_ih, b_hh, wfrag,
                                          deg, (int)(zbytes/4));   // also zeroes deg+spillc
    k_fillcast<<<castb+edgeb, 256, 0, stream>>>(srcp, dstp, e, deg, csr, spill, spillc, nper,
                                                x, y0, n*CDIM/4, castb, edgeb);
    k_agg     <<<rb, 256, 0, stream>>>(y0, csr, deg, spill, spillc, aggbuf, n);
    k_mgemm   <<<gb, 256, 0, stream>>>(aggbuf, wfrag, out, n);
}

// Round 12
// 258.699 us; speedup vs baseline: 1.2423x; 1.0730x over previous
//
#include <hip/hip_runtime.h>
#include <hip/hip_bf16.h>
#include <math.h>

typedef __hip_bfloat16  bf16_t;
typedef __attribute__((ext_vector_type(8))) short  short8;   // 8 bf16 (4 VGPRs)
typedef __attribute__((ext_vector_type(4))) float  f32x4;
typedef __attribute__((ext_vector_type(4))) int    intv4;

#define CDIM 128
#define PBCAP 15000        // per-bucket capacity (pairs & csr); Poisson mean ~8.2K, +75 sigma safe

static __device__ __forceinline__ float sigm(float x){ return 1.0f/(1.0f+__expf(-x)); }
static __device__ __forceinline__ float bflo(unsigned u){ return __builtin_bit_cast(float, u << 16); }
static __device__ __forceinline__ float bfhi(unsigned u){ return __builtin_bit_cast(float, u & 0xffff0000u); }
static __device__ __forceinline__ unsigned short f2bf_u(float f){
    __hip_bfloat16 h = __float2bfloat16(f);
    return __builtin_bit_cast(unsigned short, h);
}
static __device__ __forceinline__ unsigned packbf(float a, float b){
    return (unsigned)f2bf_u(a) | ((unsigned)f2bf_u(b) << 16);
}
static __device__ __forceinline__ short f2bf_s(float f){
    return (short)f2bf_u(f);
}

// ---------- 1. LSTM single step -> w_new in MFMA B-frag layout; also zeroes gcur ----------
// wfrag short index: ((t*8+n0)*64 + quad*16+mm)*8 + jj  <=>  B[k=32t+quad*8+jj][n=n0*16+mm]
__global__ void k_lstm(const float* __restrict__ weight, const float* __restrict__ w_ih,
                       const float* __restrict__ b_ih,   const float* __restrict__ b_hh,
                       short* __restrict__ wfrag, int* __restrict__ zptr, int zcount){
    const int gtid = blockIdx.x*CDIM + threadIdx.x;
    for(int i = gtid; i < zcount; i += CDIM*CDIM) zptr[i] = 0;

    __shared__ float wrow[CDIM];
    const int r = blockIdx.x, j = threadIdx.x;
    wrow[j] = weight[r*CDIM + j];
    __syncthreads();
    const float4* wi = (const float4*)(w_ih + (size_t)j*CDIM);
    const float4* wg = (const float4*)(w_ih + (size_t)(2*CDIM + j)*CDIM);
    const float4* wo = (const float4*)(w_ih + (size_t)(3*CDIM + j)*CDIM);
    const float4* wr = (const float4*)wrow;
    float si = 0.f, sg = 0.f, so = 0.f;
    #pragma unroll 8
    for(int k = 0; k < CDIM/4; k++){
        float4 w4 = wr[k];
        float4 a = wi[k]; si += w4.x*a.x + w4.y*a.y + w4.z*a.z + w4.w*a.w;
        float4 b = wg[k]; sg += w4.x*b.x + w4.y*b.y + w4.z*b.z + w4.w*b.w;
        float4 c = wo[k]; so += w4.x*c.x + w4.y*c.y + w4.z*c.z + w4.w*c.w;
    }
    si += b_ih[j]        + b_hh[j];
    sg += b_ih[2*CDIM+j] + b_hh[2*CDIM+j];
    so += b_ih[3*CDIM+j] + b_hh[3*CDIM+j];
    float c  = sigm(si)*tanhf(sg);           // f-gate * c0 = 0
    float wv = sigm(so)*tanhf(c);
    const int t = r >> 5, quad = (r >> 3) & 3, jj = r & 7;   // uniform per block
    const int n0 = j >> 4, mm = j & 15;
    wfrag[((size_t)((t*8 + n0)*64 + quad*16 + mm))*8 + jj] = f2bf_s(wv);
}

// ---------- 2. bucket scatter (ATOMIC-FREE per edge) + riding y0 = bf16(x) cast ----------
// The per-edge global atomic is a ~21.6 G/s hardware wall (74us for 1.6M, invariant across
// six rewrites at 26% HBM / 5% VALU). Eliminate it: per block, LDS-histogram the chunk into
// coarse buckets (dst>>9), reserve ranges with ONE global atomicAdd per (block,bucket)
// (~150K total, 10x fewer), then scatter (src,dst) pairs via LDS cursors. Cast rides along.
__global__ __launch_bounds__(256) void k_bucket(const int* __restrict__ src, const int* __restrict__ dst,
        int e, int* __restrict__ gcur, int2* __restrict__ pairs, int nbuk,
        const float* __restrict__ x, bf16_t* __restrict__ y0, int nf4,
        int castb, int sctb){
    if((int)blockIdx.x < castb){
        const float4* xv = (const float4*)x;
        uint2* yv = (uint2*)y0;
        const int t0   = blockIdx.x*256 + threadIdx.x;
        const int step = castb*256;
        for(int i = t0; i < nf4; i += step){
            float4 v = xv[i];
            uint2 o; o.x = packbf(v.x, v.y); o.y = packbf(v.z, v.w);
            yv[i] = o;
        }
        return;
    }
    __shared__ int hist[512];      // bucket counts, then bucket-local cursors
    __shared__ int gbase[512];     // reserved global base per bucket
    const int b   = (int)blockIdx.x - castb;
    const int tid = threadIdx.x;
    for(int t = tid; t < nbuk; t += 256) hist[t] = 0;
    __syncthreads();

    const int e4 = e >> 2;
    const int step = sctb*256;
    const intv4* d4 = (const intv4*)dst;
    const intv4* s4 = (const intv4*)src;
    // phase 1: histogram (deterministic grid-stride; phase 2 revisits same indices)
    for(int i = b*256 + tid; i < e4; i += step){
        intv4 d = d4[i];
        #pragma unroll
        for(int c = 0; c < 4; c++) atomicAdd(&hist[d[c] >> 9], 1);
    }
    for(int k = e4*4 + b*256 + tid; k < e; k += step)
        atomicAdd(&hist[dst[k] >> 9], 1);
    __syncthreads();
    // reserve global ranges; reset hist for reuse as cursor
    for(int t = tid; t < nbuk; t += 256){
        int c = hist[t];
        gbase[t] = c ? atomicAdd(&gcur[t], c) : 0;
        hist[t] = 0;
    }
    __syncthreads();
    // phase 2: scatter pairs into bucket regions
    for(int i = b*256 + tid; i < e4; i += step){
        intv4 d = d4[i];
        intv4 s = s4[i];
        #pragma unroll
        for(int c = 0; c < 4; c++){
            int bk = d[c] >> 9;
            int r  = atomicAdd(&hist[bk], 1);
            int pos = gbase[bk] + r;
            if(pos < PBCAP) pairs[(size_t)bk*PBCAP + pos] = make_int2(s[c], d[c]);
        }
    }
    for(int k = e4*4 + b*256 + tid; k < e; k += step){
        int dv = dst[k], bk = dv >> 9;
        int r  = atomicAdd(&hist[bk], 1);
        int pos = gbase[bk] + r;
        if(pos < PBCAP) pairs[(size_t)bk*PBCAP + pos] = make_int2(src[k], dv);
    }
}

// ---------- 3. per-bucket counting sort -> compact CSR + deg + offs (LDS atomics only) ----------
// One block per bucket (512 nodes). LDS 512-counter histogram -> wave-0 scan -> deg/offs,
// then LDS-cursor scatter of srcs into the bucket's compact csr region. No KCAP, no spill.
__global__ __launch_bounds__(256) void k_csrify(const int2* __restrict__ pairs,
        const int* __restrict__ gcur, int* __restrict__ deg, int* __restrict__ offs,
        int* __restrict__ csr, int n, int nbuk){
    __shared__ int cnt[512];
    __shared__ int scn[512];
    const int bk  = (int)blockIdx.x;
    const int tid = threadIdx.x;
    const int lo  = bk << 9;
    int nn = n - lo; if(nn > 512) nn = 512;
    cnt[tid] = 0; cnt[256 + tid] = 0;
    __syncthreads();
    int bc = gcur[bk]; if(bc > PBCAP) bc = PBCAP;
    const int2* bp = pairs + (size_t)bk*PBCAP;
    for(int i = tid; i < bc; i += 256) atomicAdd(&cnt[bp[i].y & 511], 1);
    __syncthreads();
    // exclusive scan of cnt[0..512) by wave 0: lane l owns [8l, 8l+8)
    if(tid < 64){
        int v[8];
        int s = 0;
        #pragma unroll
        for(int k = 0; k < 8; k++){ int t = cnt[tid*8 + k]; v[k] = s; s += t; }
        int run = s;
        #pragma unroll
        for(int off = 1; off < 64; off <<= 1){
            int o = __shfl_up(run, off, 64);
            if(tid >= off) run += o;
        }
        int lanebase = run - s;
        #pragma unroll
        for(int k = 0; k < 8; k++) scn[tid*8 + k] = lanebase + v[k];
    }
    __syncthreads();
    // per-node deg / offs (compact csr base = bk*PBCAP + scan)
    for(int t = tid; t < nn; t += 256){
        deg[lo + t]  = cnt[t];
        offs[lo + t] = bk*PBCAP + scn[t];
    }
    __syncthreads();
    cnt[tid] = 0; cnt[256 + tid] = 0;     // reuse as cursor
    __syncthreads();
    for(int i = tid; i < bc; i += 256){
        int2 p = bp[i];
        int l = p.y & 511;
        int r = atomicAdd(&cnt[l], 1);
        csr[(size_t)bk*PBCAP + scn[l] + r] = p.x;
    }
}

// ---------- 4. aggregate: agg[i] = bf16( di * ( sum_j dinv_j*y0_j + di*y0_i ) ) ----------
// One wave per node (proven best R4/R6). quad q handles neighbors (4t+q); 8 deg loads +
// 8 full-row uint4 gathers per quad in flight. Compact CSR via offs/deg; 32-wide outer
// loop handles any degree exactly (1 iteration for deg<=32, the vast majority).
__global__ __launch_bounds__(256) void k_agg(const bf16_t* __restrict__ y, const int* __restrict__ csr,
                      const int* __restrict__ deg, const int* __restrict__ offs,
                      bf16_t* __restrict__ agg, int n){
    const int node = (int)(((size_t)blockIdx.x*256 + threadIdx.x) >> 6);
    if(node >= n) return;
    const int lane = threadIdx.x & 63;
    const int q = lane >> 4, f = lane & 15;
    const int   cnt = deg[node];
    const int   off = offs[node];
    const float di  = rsqrtf((float)(cnt + 1));
    const uint4* yrow = (const uint4*)y;               // 16 uint4 per row
    uint4 sv = yrow[(size_t)node*16 + f];              // self row (unscaled bf16)

    float acc[8];
    #pragma unroll
    for(int i = 0; i < 8; i++) acc[i] = 0.f;

    for(int kb = 0; kb < cnt; kb += 32){
        int mm = cnt - kb; if(mm > 32) mm = 32;
        int jid = (lane < mm) ? csr[off + kb + lane] : 0;

        int jv[8];
        #pragma unroll
        for(int t = 0; t < 8; t++) jv[t] = __shfl(jid, 4*t + q, 64);

        int dgv[8];
        #pragma unroll
        for(int t = 0; t < 8; t++)
            if(4*t + q < mm) dgv[t] = deg[jv[t]];                // broadcast loads first

        uint4 v[8];
        #pragma unroll
        for(int t = 0; t < 8; t++)
            if(4*t + q < mm) v[t] = yrow[(size_t)jv[t]*16 + f];  // all rows in flight

        #pragma unroll
        for(int t = 0; t < 8; t++){
            if(4*t + q < mm){
                float dj = rsqrtf((float)(dgv[t] + 1));
                acc[0] += dj*bflo(v[t].x); acc[1] += dj*bfhi(v[t].x);
                acc[2] += dj*bflo(v[t].y); acc[3] += dj*bfhi(v[t].y);
                acc[4] += dj*bflo(v[t].z); acc[5] += dj*bfhi(v[t].z);
                acc[6] += dj*bflo(v[t].w); acc[7] += dj*bfhi(v[t].w);
            }
        }
    }
    #pragma unroll
    for(int i = 0; i < 8; i++){
        acc[i] += __shfl_xor(acc[i], 16, 64);
        acc[i] += __shfl_xor(acc[i], 32, 64);
    }
    if(q == 0){
        uint4 o;
        o.x = packbf(di*(acc[0] + di*bflo(sv.x)), di*(acc[1] + di*bfhi(sv.x)));
        o.y = packbf(di*(acc[2] + di*bflo(sv.y)), di*(acc[3] + di*bfhi(sv.y)));
        o.z = packbf(di*(acc[4] + di*bflo(sv.z)), di*(acc[5] + di*bfhi(sv.z)));
        o.w = packbf(di*(acc[6] + di*bflo(sv.w)), di*(acc[7] + di*bfhi(sv.w)));
        ((uint4*)agg)[(size_t)node*16 + f] = o;
    }
}

// ---------- 5. out = agg(bf16) @ W(bf16 frags) via MFMA, f32 out ----------
__global__ __launch_bounds__(256) void k_mgemm(const bf16_t* __restrict__ agg,
                                               const short* __restrict__ wfrag,
                                               float* __restrict__ out, int n){
    const int wid  = blockIdx.x*4 + (threadIdx.x >> 6);   // one wave per 16-row stripe
    const int row0 = wid*16;
    if(row0 >= n) return;
    const int lane = threadIdx.x & 63;
    const int m    = lane & 15, quad = lane >> 4;
    int arow = row0 + m; if(arow > n-1) arow = n-1;
    const short* ap = (const short*)agg + (size_t)arow*CDIM + quad*8;
    short8 a0 = *(const short8*)(ap);
    short8 a1 = *(const short8*)(ap + 32);
    short8 a2 = *(const short8*)(ap + 64);
    short8 a3 = *(const short8*)(ap + 96);
    const short8* bp = (const short8*)wfrag;
    float* orow = out + (size_t)(row0 + quad*4)*CDIM + m;
    const bool full = (row0 + 16 <= n);
    #pragma unroll
    for(int n0 = 0; n0 < 8; n0++){
        f32x4 acc = {0.f, 0.f, 0.f, 0.f};
        acc = __builtin_amdgcn_mfma_f32_16x16x32_bf16(a0, bp[(0*8+n0)*64 + lane], acc, 0, 0, 0);
        acc = __builtin_amdgcn_mfma_f32_16x16x32_bf16(a1, bp[(1*8+n0)*64 + lane], acc, 0, 0, 0);
        acc = __builtin_amdgcn_mfma_f32_16x16x32_bf16(a2, bp[(2*8+n0)*64 + lane], acc, 0, 0, 0);
        acc = __builtin_amdgcn_mfma_f32_16x16x32_bf16(a3, bp[(3*8+n0)*64 + lane], acc, 0, 0, 0);
        if(full){
            #pragma unroll
            for(int r = 0; r < 4; r++)
                orow[(size_t)r*CDIM + n0*16] = acc[r];
        } else {
            #pragma unroll
            for(int r = 0; r < 4; r++)
                if(row0 + quad*4 + r < n) orow[(size_t)r*CDIM + n0*16] = acc[r];
        }
    }
}

extern "C" void kernel_launch(void* const* d_in, const int* in_sizes, int n_in,
                              void* d_out, int out_size, void* d_ws, size_t ws_size,
                              hipStream_t stream){
    const float* x      = (const float*)d_in[0];
    const int*   ei     = (const int*)  d_in[1];
    const float* weight = (const float*)d_in[2];
    const float* w_ih   = (const float*)d_in[3];
    // d_in[4] = w_hh: zero forward contribution (h0 = 0)
    const float* b_ih   = (const float*)d_in[5];
    const float* b_hh   = (const float*)d_in[6];
    float* out = (float*)d_out;

    const int n = in_sizes[0]/CDIM;   // 100000
    const int e = in_sizes[1]/2;      // 1600000
    const int* srcp = ei;
    const int* dstp = ei + e;
    const int nbuk = (n + 511) >> 9;  // 196 buckets of 512 nodes

    // ws: 0.03 + ~0.001 + 0.4 + 0.4 + 11.76 + 25.6 = ~38.2 MB (< 38.87 proven R2-R11)
    auto alignup = [](size_t v){ return (v + 255) & ~(size_t)255; };
    char*  base = (char*)d_ws;
    size_t o = 0;
    short*  wfrag  = (short*) (base+o); o += alignup((size_t)CDIM*CDIM*sizeof(short));
    int*    gcur   = (int*)   (base+o); o += alignup((size_t)nbuk*4);       // zero region
    size_t  zbytes = (size_t)((char*)(base+o) - (char*)gcur);
    int*    deg    = (int*)   (base+o); o += alignup((size_t)n*4);
    int*    offs   = (int*)   (base+o); o += alignup((size_t)n*4);
    int*    csr    = (int*)   (base+o); o += alignup((size_t)nbuk*PBCAP*4); // 11.76 MB compact CSR
    bf16_t* aggbuf = (bf16_t*)(base+o); // n*CDIM*2 = 25.6 MB

    // d_out (51.2 MB) doubles as scratch until k_mgemm overwrites it last:
    //   [0, 25.6 MB)     : y0 = bf16(x) (unscaled)
    //   [25.6, 49.1 MB)  : pair buffer (int2, nbuk*PBCAP = 23.5 MB)
    bf16_t* y0    = (bf16_t*)d_out;
    int2*   pairs = (int2*)((char*)d_out + (size_t)n*CDIM*sizeof(bf16_t));

    const int castb = 512;                    // cast blocks riding the bucket kernel
    const int sctb  = 768;                    // scatter blocks
    const int rb = (n + 3)/4;                 // k_agg: 4 waves (nodes) per block
    const int gw = (n + 15)/16;               // k_mgemm: 16-row stripes
    const int gb = (gw + 3)/4;

    k_lstm   <<<CDIM, CDIM, 0, stream>>>(weight, w_ih, b_ih, b_hh, wfrag,
                                         gcur, (int)(zbytes/4));   // also zeroes gcur
    k_bucket <<<castb+sctb, 256, 0, stream>>>(srcp, dstp, e, gcur, pairs, nbuk,
                                              x, y0, n*CDIM/4, castb, sctb);
    k_csrify <<<nbuk, 256, 0, stream>>>(pairs, gcur, deg, offs, csr, n, nbuk);
    k_agg    <<<rb, 256, 0, stream>>>(y0, csr, deg, offs, aggbuf, n);
    k_mgemm  <<<gb, 256, 0, stream>>>(aggbuf, wfrag, out, n);
}

// Round 13
// 253.497 us; speedup vs baseline: 1.2678x; 1.0205x over previous
//
#include <hip/hip_runtime.h>
#include <hip/hip_bf16.h>
#include <math.h>

typedef __hip_bfloat16  bf16_t;
typedef __attribute__((ext_vector_type(8))) short  short8;   // 8 bf16 (4 VGPRs)
typedef __attribute__((ext_vector_type(4))) float  f32x4;
typedef __attribute__((ext_vector_type(4))) int    intv4;

#define CDIM 128
#define PBCAP 15000        // per-bucket capacity (pairs & csr); Poisson mean ~8.2K, +75 sigma safe

static __device__ __forceinline__ float sigm(float x){ return 1.0f/(1.0f+__expf(-x)); }
static __device__ __forceinline__ float bflo(unsigned u){ return __builtin_bit_cast(float, u << 16); }
static __device__ __forceinline__ float bfhi(unsigned u){ return __builtin_bit_cast(float, u & 0xffff0000u); }
static __device__ __forceinline__ unsigned short f2bf_u(float f){
    __hip_bfloat16 h = __float2bfloat16(f);
    return __builtin_bit_cast(unsigned short, h);
}
static __device__ __forceinline__ unsigned packbf(float a, float b){
    return (unsigned)f2bf_u(a) | ((unsigned)f2bf_u(b) << 16);
}
static __device__ __forceinline__ short f2bf_s(float f){
    return (short)f2bf_u(f);
}

// ---------- 1. LSTM single step -> w_new in MFMA B-frag layout; also zeroes gcur ----------
// wfrag short index: ((t*8+n0)*64 + quad*16+mm)*8 + jj  <=>  B[k=32t+quad*8+jj][n=n0*16+mm]
__global__ void k_lstm(const float* __restrict__ weight, const float* __restrict__ w_ih,
                       const float* __restrict__ b_ih,   const float* __restrict__ b_hh,
                       short* __restrict__ wfrag, int* __restrict__ zptr, int zcount){
    const int gtid = blockIdx.x*CDIM + threadIdx.x;
    for(int i = gtid; i < zcount; i += CDIM*CDIM) zptr[i] = 0;

    __shared__ float wrow[CDIM];
    const int r = blockIdx.x, j = threadIdx.x;
    wrow[j] = weight[r*CDIM + j];
    __syncthreads();
    const float4* wi = (const float4*)(w_ih + (size_t)j*CDIM);
    const float4* wg = (const float4*)(w_ih + (size_t)(2*CDIM + j)*CDIM);
    const float4* wo = (const float4*)(w_ih + (size_t)(3*CDIM + j)*CDIM);
    const float4* wr = (const float4*)wrow;
    float si = 0.f, sg = 0.f, so = 0.f;
    #pragma unroll 8
    for(int k = 0; k < CDIM/4; k++){
        float4 w4 = wr[k];
        float4 a = wi[k]; si += w4.x*a.x + w4.y*a.y + w4.z*a.z + w4.w*a.w;
        float4 b = wg[k]; sg += w4.x*b.x + w4.y*b.y + w4.z*b.z + w4.w*b.w;
        float4 c = wo[k]; so += w4.x*c.x + w4.y*c.y + w4.z*c.z + w4.w*c.w;
    }
    si += b_ih[j]        + b_hh[j];
    sg += b_ih[2*CDIM+j] + b_hh[2*CDIM+j];
    so += b_ih[3*CDIM+j] + b_hh[3*CDIM+j];
    float c  = sigm(si)*tanhf(sg);           // f-gate * c0 = 0
    float wv = sigm(so)*tanhf(c);
    const int t = r >> 5, quad = (r >> 3) & 3, jj = r & 7;   // uniform per block
    const int n0 = j >> 4, mm = j & 15;
    wfrag[((size_t)((t*8 + n0)*64 + quad*16 + mm))*8 + jj] = f2bf_s(wv);
}

// ---------- 2. bucket scatter (ATOMIC-FREE per edge) + riding y0 = bf16(x) cast ----------
// Replaces the ~21.6 G/s per-edge global-atomic wall (R12 win). Per block: LDS-histogram
// the chunk into coarse buckets (dst>>9), reserve ranges with ONE global atomicAdd per
// (block,bucket) (~150K total), scatter PACKED 4B entries (src | local_dst<<17; n<2^17)
// via LDS cursors -- half of R12's 8B int2 traffic. NT edge loads keep the 25.6MB edge
// stream from evicting the ~150K open pair-lines, so writeback stays ~= payload.
__global__ __launch_bounds__(256) void k_bucket(const int* __restrict__ src, const int* __restrict__ dst,
        int e, int* __restrict__ gcur, unsigned* __restrict__ pairs, int nbuk,
        const float* __restrict__ x, bf16_t* __restrict__ y0, int nf4,
        int castb, int sctb){
    if((int)blockIdx.x < castb){
        const float4* xv = (const float4*)x;
        uint2* yv = (uint2*)y0;
        const int t0   = blockIdx.x*256 + threadIdx.x;
        const int step = castb*256;
        for(int i = t0; i < nf4; i += step){
            float4 v = xv[i];
            uint2 o; o.x = packbf(v.x, v.y); o.y = packbf(v.z, v.w);
            yv[i] = o;
        }
        return;
    }
    __shared__ int hist[512];      // bucket counts, then bucket-local cursors
    __shared__ int gbase[512];     // reserved global base per bucket
    const int b   = (int)blockIdx.x - castb;
    const int tid = threadIdx.x;
    for(int t = tid; t < nbuk; t += 256) hist[t] = 0;
    __syncthreads();

    const int e4 = e >> 2;
    const int step = sctb*256;
    const intv4* d4 = (const intv4*)dst;
    const intv4* s4 = (const intv4*)src;
    // phase 1: histogram (deterministic grid-stride; phase 2 revisits same indices)
    for(int i = b*256 + tid; i < e4; i += step){
        intv4 d = __builtin_nontemporal_load(d4 + i);
        #pragma unroll
        for(int c = 0; c < 4; c++) atomicAdd(&hist[d[c] >> 9], 1);
    }
    for(int k = e4*4 + b*256 + tid; k < e; k += step)
        atomicAdd(&hist[dst[k] >> 9], 1);
    __syncthreads();
    // reserve global ranges; reset hist for reuse as cursor
    for(int t = tid; t < nbuk; t += 256){
        int c = hist[t];
        gbase[t] = c ? atomicAdd(&gcur[t], c) : 0;
        hist[t] = 0;
    }
    __syncthreads();
    // phase 2: scatter packed entries into bucket regions
    for(int i = b*256 + tid; i < e4; i += step){
        intv4 d = __builtin_nontemporal_load(d4 + i);
        intv4 s = __builtin_nontemporal_load(s4 + i);
        #pragma unroll
        for(int c = 0; c < 4; c++){
            int dv = d[c], bk = dv >> 9;
            int r  = atomicAdd(&hist[bk], 1);
            int pos = gbase[bk] + r;
            if(pos < PBCAP)
                pairs[(size_t)bk*PBCAP + pos] = (unsigned)s[c] | ((unsigned)(dv & 511) << 17);
        }
    }
    for(int k = e4*4 + b*256 + tid; k < e; k += step){
        int dv = dst[k], bk = dv >> 9;
        int r  = atomicAdd(&hist[bk], 1);
        int pos = gbase[bk] + r;
        if(pos < PBCAP)
            pairs[(size_t)bk*PBCAP + pos] = (unsigned)src[k] | ((unsigned)(dv & 511) << 17);
    }
}

// ---------- 3. per-bucket counting sort -> compact CSR + deg + offs (LDS atomics only) ----------
// One block per bucket (512 nodes). LDS 512-counter histogram -> wave-0 scan -> deg/offs,
// then LDS-cursor scatter of srcs into the bucket's compact csr region.
__global__ __launch_bounds__(256) void k_csrify(const unsigned* __restrict__ pairs,
        const int* __restrict__ gcur, int* __restrict__ deg, int* __restrict__ offs,
        int* __restrict__ csr, int n, int nbuk){
    __shared__ int cnt[512];
    __shared__ int scn[512];
    const int bk  = (int)blockIdx.x;
    const int tid = threadIdx.x;
    const int lo  = bk << 9;
    int nn = n - lo; if(nn > 512) nn = 512;
    cnt[tid] = 0; cnt[256 + tid] = 0;
    __syncthreads();
    int bc = gcur[bk]; if(bc > PBCAP) bc = PBCAP;
    const unsigned* bp = pairs + (size_t)bk*PBCAP;
    for(int i = tid; i < bc; i += 256) atomicAdd(&cnt[(bp[i] >> 17) & 511], 1);
    __syncthreads();
    // exclusive scan of cnt[0..512) by wave 0: lane l owns [8l, 8l+8)
    if(tid < 64){
        int v[8];
        int s = 0;
        #pragma unroll
        for(int k = 0; k < 8; k++){ int t = cnt[tid*8 + k]; v[k] = s; s += t; }
        int run = s;
        #pragma unroll
        for(int off = 1; off < 64; off <<= 1){
            int o = __shfl_up(run, off, 64);
            if(tid >= off) run += o;
        }
        int lanebase = run - s;
        #pragma unroll
        for(int k = 0; k < 8; k++) scn[tid*8 + k] = lanebase + v[k];
    }
    __syncthreads();
    // per-node deg / offs (compact csr base = bk*PBCAP + scan)
    for(int t = tid; t < nn; t += 256){
        deg[lo + t]  = cnt[t];
        offs[lo + t] = bk*PBCAP + scn[t];
    }
    __syncthreads();
    cnt[tid] = 0; cnt[256 + tid] = 0;     // reuse as cursor
    __syncthreads();
    for(int i = tid; i < bc; i += 256){
        unsigned p = bp[i];
        int l = (p >> 17) & 511;
        int r = atomicAdd(&cnt[l], 1);
        csr[(size_t)bk*PBCAP + scn[l] + r] = (int)(p & 0x1FFFFu);
    }
}

// ---------- 4. aggregate: agg[i] = bf16( di * ( sum_j dinv_j*y0_j + di*y0_i ) ) ----------
// One wave per node (proven best R4/R6/R12). quad q handles neighbors (4t+q); 8 deg loads
// + 8 full-row uint4 gathers per quad in flight. Compact CSR via offs/deg; 32-wide outer
// loop handles any degree exactly (1 iteration for deg<=32, the vast majority).
__global__ __launch_bounds__(256) void k_agg(const bf16_t* __restrict__ y, const int* __restrict__ csr,
                      const int* __restrict__ deg, const int* __restrict__ offs,
                      bf16_t* __restrict__ agg, int n){
    const int node = (int)(((size_t)blockIdx.x*256 + threadIdx.x) >> 6);
    if(node >= n) return;
    const int lane = threadIdx.x & 63;
    const int q = lane >> 4, f = lane & 15;
    const int   cnt = deg[node];
    const int   off = offs[node];
    const float di  = rsqrtf((float)(cnt + 1));
    const uint4* yrow = (const uint4*)y;               // 16 uint4 per row
    uint4 sv = yrow[(size_t)node*16 + f];              // self row (unscaled bf16)

    float acc[8];
    #pragma unroll
    for(int i = 0; i < 8; i++) acc[i] = 0.f;

    for(int kb = 0; kb < cnt; kb += 32){
        int mm = cnt - kb; if(mm > 32) mm = 32;
        int jid = (lane < mm) ? csr[off + kb + lane] : 0;

        int jv[8];
        #pragma unroll
        for(int t = 0; t < 8; t++) jv[t] = __shfl(jid, 4*t + q, 64);

        int dgv[8];
        #pragma unroll
        for(int t = 0; t < 8; t++)
            if(4*t + q < mm) dgv[t] = deg[jv[t]];                // broadcast loads first

        uint4 v[8];
        #pragma unroll
        for(int t = 0; t < 8; t++)
            if(4*t + q < mm) v[t] = yrow[(size_t)jv[t]*16 + f];  // all rows in flight

        #pragma unroll
        for(int t = 0; t < 8; t++){
            if(4*t + q < mm){
                float dj = rsqrtf((float)(dgv[t] + 1));
                acc[0] += dj*bflo(v[t].x); acc[1] += dj*bfhi(v[t].x);
                acc[2] += dj*bflo(v[t].y); acc[3] += dj*bfhi(v[t].y);
                acc[4] += dj*bflo(v[t].z); acc[5] += dj*bfhi(v[t].z);
                acc[6] += dj*bflo(v[t].w); acc[7] += dj*bfhi(v[t].w);
            }
        }
    }
    #pragma unroll
    for(int i = 0; i < 8; i++){
        acc[i] += __shfl_xor(acc[i], 16, 64);
        acc[i] += __shfl_xor(acc[i], 32, 64);
    }
    if(q == 0){
        uint4 o;
        o.x = packbf(di*(acc[0] + di*bflo(sv.x)), di*(acc[1] + di*bfhi(sv.x)));
        o.y = packbf(di*(acc[2] + di*bflo(sv.y)), di*(acc[3] + di*bfhi(sv.y)));
        o.z = packbf(di*(acc[4] + di*bflo(sv.z)), di*(acc[5] + di*bfhi(sv.z)));
        o.w = packbf(di*(acc[6] + di*bflo(sv.w)), di*(acc[7] + di*bfhi(sv.w)));
        ((uint4*)agg)[(size_t)node*16 + f] = o;
    }
}

// ---------- 5. out = agg(bf16) @ W(bf16 frags) via MFMA, f32 out ----------
__global__ __launch_bounds__(256) void k_mgemm(const bf16_t* __restrict__ agg,
                                               const short* __restrict__ wfrag,
                                               float* __restrict__ out, int n){
    const int wid  = blockIdx.x*4 + (threadIdx.x >> 6);   // one wave per 16-row stripe
    const int row0 = wid*16;
    if(row0 >= n) return;
    const int lane = threadIdx.x & 63;
    const int m    = lane & 15, quad = lane >> 4;
    int arow = row0 + m; if(arow > n-1) arow = n-1;
    const short* ap = (const short*)agg + (size_t)arow*CDIM + quad*8;
    short8 a0 = *(const short8*)(ap);
    short8 a1 = *(const short8*)(ap + 32);
    short8 a2 = *(const short8*)(ap + 64);
    short8 a3 = *(const short8*)(ap + 96);
    const short8* bp = (const short8*)wfrag;
    float* orow = out + (size_t)(row0 + quad*4)*CDIM + m;
    const bool full = (row0 + 16 <= n);
    #pragma unroll
    for(int n0 = 0; n0 < 8; n0++){
        f32x4 acc = {0.f, 0.f, 0.f, 0.f};
        acc = __builtin_amdgcn_mfma_f32_16x16x32_bf16(a0, bp[(0*8+n0)*64 + lane], acc, 0, 0, 0);
        acc = __builtin_amdgcn_mfma_f32_16x16x32_bf16(a1, bp[(1*8+n0)*64 + lane], acc, 0, 0, 0);
        acc = __builtin_amdgcn_mfma_f32_16x16x32_bf16(a2, bp[(2*8+n0)*64 + lane], acc, 0, 0, 0);
        acc = __builtin_amdgcn_mfma_f32_16x16x32_bf16(a3, bp[(3*8+n0)*64 + lane], acc, 0, 0, 0);
        if(full){
            #pragma unroll
            for(int r = 0; r < 4; r++)
                orow[(size_t)r*CDIM + n0*16] = acc[r];
        } else {
            #pragma unroll
            for(int r = 0; r < 4; r++)
                if(row0 + quad*4 + r < n) orow[(size_t)r*CDIM + n0*16] = acc[r];
        }
    }
}

extern "C" void kernel_launch(void* const* d_in, const int* in_sizes, int n_in,
                              void* d_out, int out_size, void* d_ws, size_t ws_size,
                              hipStream_t stream){
    const float* x      = (const float*)d_in[0];
    const int*   ei     = (const int*)  d_in[1];
    const float* weight = (const float*)d_in[2];
    const float* w_ih   = (const float*)d_in[3];
    // d_in[4] = w_hh: zero forward contribution (h0 = 0)
    const float* b_ih   = (const float*)d_in[5];
    const float* b_hh   = (const float*)d_in[6];
    float* out = (float*)d_out;

    const int n = in_sizes[0]/CDIM;   // 100000  (< 2^17: packed-pair encoding valid)
    const int e = in_sizes[1]/2;      // 1600000
    const int* srcp = ei;
    const int* dstp = ei + e;
    const int nbuk = (n + 511) >> 9;  // 196 buckets of 512 nodes

    // ws: 0.03 + ~0.001 + 0.4 + 0.4 + 11.76 + 25.6 = ~38.2 MB (< 38.87 proven R2-R12)
    auto alignup = [](size_t v){ return (v + 255) & ~(size_t)255; };
    char*  base = (char*)d_ws;
    size_t o = 0;
    short*  wfrag  = (short*) (base+o); o += alignup((size_t)CDIM*CDIM*sizeof(short));
    int*    gcur   = (int*)   (base+o); o += alignup((size_t)nbuk*4);       // zero region
    size_t  zbytes = (size_t)((char*)(base+o) - (char*)gcur);
    int*    deg    = (int*)   (base+o); o += alignup((size_t)n*4);
    int*    offs   = (int*)   (base+o); o += alignup((size_t)n*4);
    int*    csr    = (int*)   (base+o); o += alignup((size_t)nbuk*PBCAP*4); // 11.76 MB compact CSR
    bf16_t* aggbuf = (bf16_t*)(base+o); // n*CDIM*2 = 25.6 MB

    // d_out (51.2 MB) doubles as scratch until k_mgemm overwrites it last:
    //   [0, 25.6 MB)     : y0 = bf16(x) (unscaled)
    //   [25.6, 37.4 MB)  : packed pair buffer (uint, nbuk*PBCAP = 11.76 MB)
    bf16_t*   y0    = (bf16_t*)d_out;
    unsigned* pairs = (unsigned*)((char*)d_out + (size_t)n*CDIM*sizeof(bf16_t));

    const int castb = 512;                    // cast blocks riding the bucket kernel
    const int sctb  = 768;                    // scatter blocks
    const int rb = (n + 3)/4;                 // k_agg: 4 waves (nodes) per block
    const int gw = (n + 15)/16;               // k_mgemm: 16-row stripes
    const int gb = (gw + 3)/4;

    k_lstm   <<<CDIM, CDIM, 0, stream>>>(weight, w_ih, b_ih, b_hh, wfrag,
                                         gcur, (int)(zbytes/4));   // also zeroes gcur
    k_bucket <<<castb+sctb, 256, 0, stream>>>(srcp, dstp, e, gcur, pairs, nbuk,
                                              x, y0, n*CDIM/4, castb, sctb);
    k_csrify <<<nbuk, 256, 0, stream>>>(pairs, gcur, deg, offs, csr, n, nbuk);
    k_agg    <<<rb, 256, 0, stream>>>(y0, csr, deg, offs, aggbuf, n);
    k_mgemm  <<<gb, 256, 0, stream>>>(aggbuf, wfrag, out, n);
}